// Round 1
// baseline (2783.899 us; speedup 1.0000x reference)
//
#include <hip/hip_runtime.h>
#include <hip/hip_fp16.h>
#include <hip/hip_cooperative_groups.h>
#include <stdint.h>

namespace cg = cooperative_groups;

typedef unsigned short u16;
typedef unsigned char u8;
typedef unsigned int u32;
typedef __attribute__((ext_vector_type(8))) short short8;
typedef __attribute__((ext_vector_type(4))) float f32x4;

#define NSTEP 26
#define NB 512
#define NT 128
#define NH 256
#define NCLS 100

#define SP 32.0f     // proj_H int8 scale
#define SH 24.0f     // batch_H int8 scale
#define SW 2000.0f   // W_h2h int8 scale
#define S8 127.0f    // h int8 scale

#define XCAT_STRIDE ((size_t)262144)  // u16 elements per parity buffer

#if defined(__has_builtin)
#if __has_builtin(__builtin_amdgcn_sdot4)
#define HAS_SDOT4 1
#endif
#endif

__device__ __forceinline__ u16 f2bf(float f) {
    unsigned u = __float_as_uint(f);
    return (u16)((u + 0x7FFFu + ((u >> 16) & 1u)) >> 16);
}
__device__ __forceinline__ int q8i(float x, float s) {
    float v = fminf(fmaxf(x * s, -127.f), 127.f);
    return __float2int_rn(v);
}
__device__ __forceinline__ float fast_tanh(float x) {
    float e = __expf(2.f * x);
    return 1.f - 2.f / (e + 1.f);
}
__device__ __forceinline__ float fast_sig(float x) { return 1.f / (1.f + __expf(-x)); }
__device__ __forceinline__ void async_g2l(const void* g, void* l) {
    __builtin_amdgcn_global_load_lds((const __attribute__((address_space(1))) u32*)g,
                                     (__attribute__((address_space(3))) u32*)l, 16, 0, 0);
}

// ---------------- prep: ALL weight conversions + XcatS(parity0) h-half zero --------
__global__ void prep_all(const float* __restrict__ W_h2h, const float* __restrict__ W_i2h,
                         const float* __restrict__ W_ih, const float* __restrict__ W_hh,
                         const float* __restrict__ b_ih, const float* __restrict__ b_hh,
                         const float* __restrict__ W_gen,
                         char* __restrict__ Wh2h_q8, u16* __restrict__ Wi2h_bf,
                         u16* __restrict__ Wcat3, float* __restrict__ bsum,
                         u16* __restrict__ WgenP, float* __restrict__ WohT,
                         u16* __restrict__ XcatS) {
    int idx = blockIdx.x * 256 + threadIdx.x;  // 65536 threads
    if (idx < 65536) {
        Wh2h_q8[idx] = (char)q8i(W_h2h[idx], SW);
        Wi2h_bf[idx] = f2bf(W_i2h[idx]);
    }
    for (int i = idx; i < 16 * 16 * 4 * 64 * 8; i += 65536) {
        int j = i & 7, lane = (i >> 3) & 63, q = (i >> 9) & 3, ks = (i >> 11) & 15, ub = i >> 15;
        int lr = lane & 15, lq = lane >> 4;
        int rg = q * 256 + ub * 16 + lr;
        int k = ks * 32 + lq * 8 + j;
        float v = (k < 256) ? W_ih[(size_t)rg * 356 + k] : W_hh[(size_t)rg * 256 + (k - 256)];
        Wcat3[i] = f2bf(v);
    }
    for (int i = idx; i < 100 * 1024; i += 65536) {
        int t = i >> 10, rg = i & 1023;
        WohT[i] = W_ih[(size_t)rg * 356 + 256 + t];
    }
    if (idx < 1024) bsum[idx] = b_ih[idx] + b_hh[idx];
    if (idx < 32768) {
        int r = idx >> 8, ccol = idx & 255;
        WgenP[idx] = (r < NCLS) ? f2bf(W_gen[r * 256 + ccol]) : (u16)0;
    }
    // zero the h-half of parity-0 XcatS (k in [256,512)): ks in [8,16)
    for (int i = idx; i < 32 * 8 * 64 * 8; i += 65536) {
        int j = i & 7, lane = (i >> 3) & 63, ks = 8 + ((i >> 9) & 7), btile = i >> 12;
        XcatS[(size_t)((btile * 16 + ks) * 64 + lane) * 8 + j] = (u16)0;
    }
}

// ---------------- proj_H GEMM: 1 batch/block, 128x256, 8 waves 2x4 (R6-proven) --------
__launch_bounds__(512, 3)
__global__ void gemm_projH5(const float* __restrict__ bH, const u16* __restrict__ Wi2h_bf,
                            char* __restrict__ projF8, char* __restrict__ bHf8T) {
    __shared__ char gsm[49152];
    u16* As[2] = {(u16*)gsm, (u16*)(gsm + 8192)};
    u16* Bs[2] = {(u16*)(gsm + 16384), (u16*)(gsm + 32768)};
    char* Tt = gsm;   // epilogue: [256 rows][144 pad] int8 (aliases As after final sync)

    int b = blockIdx.x, tid = threadIdx.x;
    int wave = tid >> 6, lane = tid & 63, lr = lane & 15, lq = lane >> 4;
    int wm = wave >> 2, wn = wave & 3;
    int ar = tid >> 2, part = tid & 3;
    const float* asrc = bH + ((size_t)b * 128 + ar) * 256 + part * 8;
    f32x4 acc[4][4] = {};
    uint2 bh[8];

    auto stageB = [&](int kc, int buf) {
        for (int i = 0; i < 2; i++) {
            int ch = wave * 2 + i;
            int row = ch * 16 + (lane >> 2);
            const u16* g = Wi2h_bf + (size_t)row * 256 + kc * 32 + (lane & 3) * 8;
            async_g2l(g, (char*)Bs[buf] + ch * 1024 + lane * 16);
        }
    };
    auto writeA = [&](int kc, int buf, float4 v0, float4 v1) {
        u16* dst = As[buf] + ar * 32 + part * 8;
        dst[0] = f2bf(v0.x); dst[1] = f2bf(v0.y); dst[2] = f2bf(v0.z); dst[3] = f2bf(v0.w);
        dst[4] = f2bf(v1.x); dst[5] = f2bf(v1.y); dst[6] = f2bf(v1.z); dst[7] = f2bf(v1.w);
        uint p0 = (uint)(u8)q8i(v0.x, SH) | ((uint)(u8)q8i(v0.y, SH) << 8) |
                  ((uint)(u8)q8i(v0.z, SH) << 16) | ((uint)(u8)q8i(v0.w, SH) << 24);
        uint p1 = (uint)(u8)q8i(v1.x, SH) | ((uint)(u8)q8i(v1.y, SH) << 8) |
                  ((uint)(u8)q8i(v1.z, SH) << 16) | ((uint)(u8)q8i(v1.w, SH) << 24);
        bh[kc].x = p0; bh[kc].y = p1;
    };

    float4 a0 = *(const float4*)(asrc);
    float4 a1 = *(const float4*)(asrc + 4);
    stageB(0, 0);
    writeA(0, 0, a0, a1);
    __syncthreads();

    for (int kc = 0; kc < 8; kc++) {
        int cur = kc & 1, nxt = cur ^ 1;
        if (kc < 7) {
            stageB(kc + 1, nxt);
            a0 = *(const float4*)(asrc + (kc + 1) * 32);
            a1 = *(const float4*)(asrc + (kc + 1) * 32 + 4);
        }
        short8 af[4];
        for (int mi = 0; mi < 4; mi++)
            af[mi] = *(const short8*)(As[cur] + (wm * 64 + mi * 16 + lr) * 32 + lq * 8);
        for (int ni = 0; ni < 4; ni++) {
            short8 bf = *(const short8*)(Bs[cur] + (wn * 64 + ni * 16 + lr) * 32 + lq * 8);
            for (int mi = 0; mi < 4; mi++)
                acc[mi][ni] = __builtin_amdgcn_mfma_f32_16x16x32_bf16(af[mi], bf, acc[mi][ni], 0, 0, 0);
        }
        if (kc < 7) writeA(kc + 1, nxt, a0, a1);
        __syncthreads();
    }

    for (int mi = 0; mi < 4; mi++)
        for (int ni = 0; ni < 4; ni++) {
            int h = wn * 64 + ni * 16 + lr;
            int t = wm * 64 + mi * 16 + lq * 4;
            f32x4 v = acc[mi][ni];
            uint pk = (uint)(u8)q8i(v[0], SP) | ((uint)(u8)q8i(v[1], SP) << 8) |
                      ((uint)(u8)q8i(v[2], SP) << 16) | ((uint)(u8)q8i(v[3], SP) << 24);
            *(uint*)(Tt + h * 144 + t) = pk;
        }
    __syncthreads();
    {
        int hrow = tid >> 1, half = tid & 1;
        const char* src = Tt + hrow * 144 + half * 64;
        char* dst = projF8 + (size_t)b * 32768 + hrow * 128 + half * 64;
        uint4 v0 = *(const uint4*)(src);
        uint4 v1 = *(const uint4*)(src + 16);
        uint4 v2 = *(const uint4*)(src + 32);
        uint4 v3 = *(const uint4*)(src + 48);
        *(uint4*)(dst) = v0; *(uint4*)(dst + 16) = v1;
        *(uint4*)(dst + 32) = v2; *(uint4*)(dst + 48) = v3;
    }
    __syncthreads();
    {
        for (int kc = 0; kc < 8; kc++) {
            uint wlo = bh[kc].x, whi = bh[kc].y;
            char* t0p = Tt + (size_t)(kc * 32 + part * 8) * 144 + ar;
            t0p[0 * 144] = (char)(wlo);       t0p[1 * 144] = (char)(wlo >> 8);
            t0p[2 * 144] = (char)(wlo >> 16); t0p[3 * 144] = (char)(wlo >> 24);
            t0p[4 * 144] = (char)(whi);       t0p[5 * 144] = (char)(whi >> 8);
            t0p[6 * 144] = (char)(whi >> 16); t0p[7 * 144] = (char)(whi >> 24);
        }
    }
    __syncthreads();
    {
        int irow = tid >> 1, half = tid & 1;
        const char* src = Tt + irow * 144 + half * 64;
        char* dst = bHf8T + (size_t)b * 32768 + irow * 128 + half * 64;
        uint4 v0 = *(const uint4*)(src);
        uint4 v1 = *(const uint4*)(src + 16);
        uint4 v2 = *(const uint4*)(src + 32);
        uint4 v3 = *(const uint4*)(src + 48);
        *(uint4*)(dst) = v0; *(uint4*)(dst + 16) = v1;
        *(uint4*)(dst + 32) = v2; *(uint4*)(dst + 48) = v3;
    }
}

// ---------------- persistent cooperative step loop: all 26 steps, 2 grid-syncs/step ----
// 256 blocks x 512 threads. Each block: 2 batches (attn, one per 256-thread half)
// and 2 LSTM jobs (threads 0..255). XcatS double-buffered by step parity (h-half race fix).
__launch_bounds__(512, 1)
__global__ void step_loop(const char* __restrict__ Wh2h_q8, const float* __restrict__ b_h2h,
                          const float* __restrict__ W_score, const char* __restrict__ projF8,
                          const char* __restrict__ bHf8T, u16* __restrict__ XcatS,
                          const u16* __restrict__ Wcat3, const float* __restrict__ bsum,
                          const float* __restrict__ WohT, const int* __restrict__ text,
                          float* __restrict__ c_st, u16* __restrict__ hbf_all,
                          char* __restrict__ h8) {
    cg::grid_group grid = cg::this_grid();

    __shared__ float ws_s[256];
    __shared__ float bh2h_s[256];
    __shared__ float ph[2][256];
    __shared__ uint4 h8s[2][16];
    __shared__ float epart[2][128 * 4];   // [half][t*4 + wave_in_half]
    __shared__ float es_exp[2][128];
    __shared__ float rinv_s[2];
    __shared__ float gq2[2][4 * 64 * 5];  // [job_in_block][gate*320 + lane*5 + r]

    int tid = threadIdx.x;
    // attn decomposition (step-invariant)
    int half = tid >> 8, htid = tid & 255;
    int b = blockIdx.x * 2 + half;
    int btile = b >> 4, blr = b & 15;
    int lane = tid & 63;
    int wv4 = htid >> 6;                 // wave within half: 0..3
    int tq = htid & 7, hg = htid >> 3;   // hg in [0,32)
    int t0e = tq * 16;
    // lstm decomposition (step-invariant; valid for tid<256)
    int jj = (tid >> 7) & 1;
    int t1 = tid & 127;
    int job = blockIdx.x * 2 + jj;
    int w2 = t1 >> 6, l2 = t1 & 63;
    int lr2 = l2 & 15, lq2 = l2 >> 4;
    int mt = job >> 4, ub = job & 15;

    if (tid < 256) { ws_s[tid] = W_score[tid]; bh2h_s[tid] = b_h2h[tid]; }
    __syncthreads();

    for (int s = 0; s < NSTEP; s++) {
        // ================= attention phase (2 batches, one per half) =================
        if (htid < 16)
            h8s[half][htid] = (s > 0) ? ((const uint4*)(h8 + (size_t)b * 256))[htid]
                                      : uint4{0, 0, 0, 0};
        __syncthreads();

        // ph[u] = b_h2h[u] + (h8 . Wq8[u,:]) / (SW*S8)
        {
            int u = htid;
            float v;
            if (s == 0) {
                v = bh2h_s[u];
            } else {
                const uint4* wrow = (const uint4*)(Wh2h_q8 + (size_t)u * 256);
                int acc = 0;
#pragma unroll
                for (int k = 0; k < 16; k++) {
                    uint4 w = wrow[k];
                    uint4 hh = h8s[half][k];
#ifdef HAS_SDOT4
                    acc = __builtin_amdgcn_sdot4((int)w.x, (int)hh.x, acc, false);
                    acc = __builtin_amdgcn_sdot4((int)w.y, (int)hh.y, acc, false);
                    acc = __builtin_amdgcn_sdot4((int)w.z, (int)hh.z, acc, false);
                    acc = __builtin_amdgcn_sdot4((int)w.w, (int)hh.w, acc, false);
#else
                    uint wv[4] = {w.x, w.y, w.z, w.w}, hv[4] = {hh.x, hh.y, hh.z, hh.w};
                    for (int c = 0; c < 4; c++)
                        for (int by = 0; by < 32; by += 8)
                            acc += (int)(char)(wv[c] >> by) * (int)(char)(hv[c] >> by);
#endif
                }
                v = (float)acc * (1.f / (SW * S8)) + bh2h_s[u];
            }
            ph[half][u] = v;
        }
        __syncthreads();

        // e[t] = sum_h tanh(projF8/SP + ph[h]) * Ws[h]; 8 rows per thread, 16 t each
        {
            const __half2 c3 = __float2half2_rn(-0.0016249f), c2 = __float2half2_rn(0.031520f);
            const __half2 c1 = __float2half2_rn(-0.222110f), c0 = __float2half2_rn(0.962117f);
            const float inv = 1.f / SP;
            __half2 acc2[8];
#pragma unroll
            for (int q = 0; q < 8; q++) acc2[q] = __float2half2_rn(0.f);
            const char* base = projF8 + (size_t)b * 32768 + t0e;
#pragma unroll
            for (int hh = 0; hh < 8; hh++) {
                int R = hg * 8 + hh;
                uint4 uu = *(const uint4*)(base + R * 128);
                float phv = ph[half][R];
                __half2 wv2 = __float2half2_rn(ws_s[R]);
                uint wq[4] = {uu.x, uu.y, uu.z, uu.w};
#pragma unroll
                for (int wi = 0; wi < 4; wi++) {
                    uint w = wq[wi];
#pragma unroll
                    for (int pp = 0; pp < 2; pp++) {
                        float xa = fmaf((float)(char)(w >> (pp * 16)), inv, phv);
                        float xb = fmaf((float)(char)(w >> (pp * 16 + 8)), inv, phv);
                        xa = fminf(fmaxf(xa, -3.0f), 3.0f);
                        xb = fminf(fmaxf(xb, -3.0f), 3.0f);
                        __half2 x = __floats2half2_rn(xa, xb);
                        __half2 u2 = __hmul2(x, x);
                        __half2 p = __hfma2(__hfma2(__hfma2(c3, u2, c2), u2, c1), u2, c0);
                        acc2[wi * 2 + pp] = __hfma2(__hmul2(x, p), wv2, acc2[wi * 2 + pp]);
                    }
                }
            }
            float a16[16];
#pragma unroll
            for (int q = 0; q < 8; q++) {
                a16[q * 2] = __low2float(acc2[q]);
                a16[q * 2 + 1] = __high2float(acc2[q]);
            }
#pragma unroll
            for (int j = 0; j < 16; j++) {
                float v = a16[j];
                v += __shfl_xor(v, 8);
                v += __shfl_xor(v, 16);
                v += __shfl_xor(v, 32);
                a16[j] = v;
            }
            if (lane < 8) {
#pragma unroll
                for (int j = 0; j < 16; j++) epart[half][(t0e + j) * 4 + wv4] = a16[j];
            }
        }
        __syncthreads();

        // softmax in wave 0 of each half
        if (wv4 == 0) {
            int t0 = lane * 2;
            float e0 = 0.f, e1 = 0.f;
#pragma unroll
            for (int w = 0; w < 4; w++) {
                e0 += epart[half][t0 * 4 + w];
                e1 += epart[half][(t0 + 1) * 4 + w];
            }
            float m = fmaxf(e0, e1);
            for (int o = 32; o >= 1; o >>= 1) m = fmaxf(m, __shfl_xor(m, o));
            float x0 = __expf(e0 - m), x1 = __expf(e1 - m);
            float ss = x0 + x1;
            for (int o = 32; o >= 1; o >>= 1) ss += __shfl_xor(ss, o);
            es_exp[half][t0] = x0; es_exp[half][t0 + 1] = x1;
            if (lane == 0) rinv_s[half] = 1.f / ss;
        }
        __syncthreads();

        // context[i] = sum_t alpha_t * bHf8T[i][t]; one thread per i, full t range
        {
            float rinv = rinv_s[half];
            int i = htid;
            const char* src = bHf8T + (size_t)b * 32768 + i * 128;
            float a = 0.f;
#pragma unroll
            for (int q = 0; q < 8; q++) {
                uint4 u4 = ((const uint4*)src)[q];
                uint wv[4] = {u4.x, u4.y, u4.z, u4.w};
#pragma unroll
                for (int c = 0; c < 4; c++) {
                    uint w = wv[c];
                    int tb = q * 16 + c * 4;
                    a += es_exp[half][tb + 0] * (float)(char)(w);
                    a += es_exp[half][tb + 1] * (float)(char)(w >> 8);
                    a += es_exp[half][tb + 2] * (float)(char)(w >> 16);
                    a += es_exp[half][tb + 3] * (float)(char)(w >> 24);
                }
            }
            int ks = i >> 5, klq = (i >> 3) & 3, j = i & 7;
            u16* Xw = XcatS + (size_t)(s & 1) * XCAT_STRIDE;
            Xw[(size_t)((btile * 16 + ks) * 64 + klq * 16 + blr) * 8 + j] =
                f2bf(a * rinv * (1.f / SH));
        }
        grid.sync();

        // ================= LSTM phase (2 jobs, threads 0..255) =================
        if (tid < 256) {
            f32x4 acc0 = {}, acc1 = {};
            const u16* Xr = XcatS + (size_t)(s & 1) * XCAT_STRIDE;
            for (int ks = 0; ks < 16; ks++) {
                short8 a = *(const short8*)(Xr + (size_t)((mt * 16 + ks) * 64 + l2) * 8);
                const u16* wb = Wcat3 + (size_t)((ub * 16 + ks) * 4 + w2 * 2) * 512 + l2 * 8;
                short8 b0 = *(const short8*)(wb);
                short8 b1 = *(const short8*)(wb + 512);
                acc0 = __builtin_amdgcn_mfma_f32_16x16x32_bf16(a, b0, acc0, 0, 0, 0);
                acc1 = __builtin_amdgcn_mfma_f32_16x16x32_bf16(a, b1, acc1, 0, 0, 0);
            }
            for (int r = 0; r < 4; r++) {
                gq2[jj][(w2 * 2) * 320 + l2 * 5 + r] = acc0[r];
                gq2[jj][(w2 * 2 + 1) * 320 + l2 * 5 + r] = acc1[r];
            }
        }
        __syncthreads();
        if (tid < 256) {
            int u = ub * 16 + lr2;
            float bi_ = bsum[u], bf_ = bsum[256 + u], bg_ = bsum[512 + u], bo_ = bsum[768 + u];
            u16* Xw = XcatS + (size_t)((s + 1) & 1) * XCAT_STRIDE;
            for (int rr = 0; rr < 2; rr++) {
                int r = w2 * 2 + rr;
                float gi = gq2[jj][0 * 320 + l2 * 5 + r];
                float gf = gq2[jj][1 * 320 + l2 * 5 + r];
                float gg = gq2[jj][2 * 320 + l2 * 5 + r];
                float go = gq2[jj][3 * 320 + l2 * 5 + r];
                int bgi = mt * 16 + lq2 * 4 + r;
                int tgt = text[bgi * NSTEP + s];
                const float* wt = WohT + (size_t)tgt * 1024;
                gi += bi_ + wt[u];
                gf += bf_ + wt[256 + u];
                gg += bg_ + wt[512 + u];
                go += bo_ + wt[768 + u];
                float cold = (s > 0) ? c_st[(size_t)bgi * 256 + u] : 0.f;
                float cn = fast_sig(gf) * cold + fast_sig(gi) * fast_tanh(gg);
                float hn = fast_sig(go) * fast_tanh(cn);
                c_st[(size_t)bgi * 256 + u] = cn;
                hbf_all[(size_t)s * NB * NH + (size_t)bgi * 256 + u] = f2bf(hn);
                h8[(size_t)bgi * 256 + u] = (char)q8i(hn, S8);
                {   // XcatS h-half for next step (opposite parity buffer)
                    int ks2 = 8 + (u >> 5), klq = (u >> 3) & 3, j = u & 7;
                    int btile2 = bgi >> 4, blr2 = bgi & 15;
                    Xw[(size_t)((btile2 * 16 + ks2) * 64 + klq * 16 + blr2) * 8 + j] = f2bf(hn);
                }
            }
        }
        grid.sync();
    }
}

// ---------------- final logits ----------------
__launch_bounds__(256)
__global__ void gen_logits(const u16* __restrict__ hbf_all, const u16* __restrict__ WgenP,
                           const float* __restrict__ b_gen, float* __restrict__ out) {
    __shared__ u16 As[32 * 32];
    __shared__ u16 Bs[128 * 32];
    int mb = blockIdx.x;
    int tid = threadIdx.x;
    int wave = tid >> 6, lane = tid & 63, lr = lane & 15, lq = lane >> 4;
    int wm = wave >> 1, wn = wave & 1;
    f32x4 acc[4] = {};
    for (int kc = 0; kc < 256; kc += 32) {
        __syncthreads();
        {
            int r = tid >> 3, c4 = (tid & 7) * 4;
            *(ushort4*)(As + r * 32 + c4) =
                *(const ushort4*)(hbf_all + (size_t)(mb * 32 + r) * 256 + kc + c4);
        }
        {
            int r = tid >> 1, h16 = (tid & 1) * 16;
            const u16* src = WgenP + (size_t)r * 256 + kc + h16;
            u16* d = Bs + r * 32 + h16;
            *(ushort4*)(d) = *(const ushort4*)(src);
            *(ushort4*)(d + 4) = *(const ushort4*)(src + 4);
            *(ushort4*)(d + 8) = *(const ushort4*)(src + 8);
            *(ushort4*)(d + 12) = *(const ushort4*)(src + 12);
        }
        __syncthreads();
        short8 a = *reinterpret_cast<const short8*>(As + (wm * 16 + lr) * 32 + lq * 8);
        for (int ni = 0; ni < 4; ni++) {
            short8 bb = *reinterpret_cast<const short8*>(Bs + (wn * 64 + ni * 16 + lr) * 32 + lq * 8);
            acc[ni] = __builtin_amdgcn_mfma_f32_16x16x32_bf16(a, bb, acc[ni], 0, 0, 0);
        }
    }
    for (int ni = 0; ni < 4; ni++) {
        int cidx = wn * 64 + ni * 16 + lr;
        if (cidx >= NCLS) continue;
        float bg = b_gen[cidx];
        int mbase = mb * 32 + wm * 16 + lq * 4;
        for (int r = 0; r < 4; r++) {
            int mm = mbase + r;
            int s = mm >> 9;
            int bb_ = mm & 511;
            float v = (cidx == 3) ? -10000.f : (acc[ni][r] + bg);
            out[(size_t)bb_ * (NSTEP * NCLS) + s * NCLS + cidx] = v;
        }
    }
}

extern "C" void kernel_launch(void* const* d_in, const int* in_sizes, int n_in,
                              void* d_out, int out_size, void* d_ws, size_t ws_size,
                              hipStream_t stream) {
    const float* batch_H = (const float*)d_in[0];
    const int* text = (const int*)d_in[1];
    const float* W_i2h = (const float*)d_in[3];
    const float* W_h2h = (const float*)d_in[4];
    const float* b_h2h = (const float*)d_in[5];
    const float* W_score = (const float*)d_in[6];
    const float* W_ih = (const float*)d_in[7];
    const float* W_hh = (const float*)d_in[8];
    const float* b_ih = (const float*)d_in[9];
    const float* b_hh = (const float*)d_in[10];
    const float* W_gen = (const float*)d_in[11];
    const float* b_gen = (const float*)d_in[12];
    float* out = (float*)d_out;

    char* ws = (char*)d_ws;
    size_t off = 0;
    auto alloc = [&](size_t bytes) {
        void* p = ws + off;
        off += (bytes + 255) & ~(size_t)255;
        return p;
    };
    char* projF8 = (char*)alloc((size_t)16777216);    // [b][h][t] int8
    char* bHf8T = (char*)alloc((size_t)16777216);     // [b][i][t] int8 (transposed)
    char* Wh2h_q8 = (char*)alloc(65536);
    u16* Wi2h_bf = (u16*)alloc(65536 * 2);
    u16* Wcat3 = (u16*)alloc((size_t)524288 * 2);     // frag-swizzled LSTM weights
    float* bsum = (float*)alloc(1024 * 4);
    u16* WgenP = (u16*)alloc(32768 * 2);
    float* WohT = (float*)alloc((size_t)102400 * 4);  // [100][1024]
    u16* XcatS = (u16*)alloc(XCAT_STRIDE * 2 * 2);    // 2 parity buffers
    u16* hbf_all = (u16*)alloc((size_t)NSTEP * NB * NH * 2);
    char* h8 = (char*)alloc((size_t)NB * NH);
    float* c_st = (float*)alloc((size_t)NB * NH * 4);

    prep_all<<<256, 256, 0, stream>>>(W_h2h, W_i2h, W_ih, W_hh, b_ih, b_hh, W_gen,
                                      Wh2h_q8, Wi2h_bf, Wcat3, bsum, WgenP, WohT, XcatS);
    gemm_projH5<<<512, 512, 0, stream>>>(batch_H, Wi2h_bf, projF8, bHf8T);

    {
        void* cargs[] = {(void*)&Wh2h_q8, (void*)&b_h2h, (void*)&W_score,
                         (void*)&projF8, (void*)&bHf8T, (void*)&XcatS,
                         (void*)&Wcat3, (void*)&bsum, (void*)&WohT,
                         (void*)&text, (void*)&c_st, (void*)&hbf_all, (void*)&h8};
        hipLaunchCooperativeKernel((const void*)step_loop, dim3(256), dim3(512),
                                   cargs, 0, stream);
    }

    gen_logits<<<416, 256, 0, stream>>>(hbf_all, WgenP, b_gen, out);
}

// Round 2
// 631.476 us; speedup vs baseline: 4.4086x; 4.4086x over previous
//
#include <hip/hip_runtime.h>
#include <hip/hip_fp16.h>
#include <stdint.h>

typedef unsigned short u16;
typedef unsigned char u8;
typedef unsigned int u32;
typedef __attribute__((ext_vector_type(8))) short short8;
typedef __attribute__((ext_vector_type(4))) float f32x4;

#define NSTEP 26
#define NB 512
#define NT 128
#define NH 256
#define NCLS 100

#define SP 32.0f     // proj_H int8 scale
#define SH 24.0f     // batch_H int8 scale
#define SW 2000.0f   // W_h2h int8 scale
#define S8 127.0f    // h int8 scale

#if defined(__has_builtin)
#if __has_builtin(__builtin_amdgcn_sdot4)
#define HAS_SDOT4 1
#endif
#endif

__device__ __forceinline__ u16 f2bf(float f) {
    unsigned u = __float_as_uint(f);
    return (u16)((u + 0x7FFFu + ((u >> 16) & 1u)) >> 16);
}
__device__ __forceinline__ int q8i(float x, float s) {
    float v = fminf(fmaxf(x * s, -127.f), 127.f);
    return __float2int_rn(v);
}
__device__ __forceinline__ float fast_tanh(float x) {
    float e = __expf(2.f * x);
    return 1.f - 2.f / (e + 1.f);
}
__device__ __forceinline__ float fast_sig(float x) { return 1.f / (1.f + __expf(-x)); }
__device__ __forceinline__ void async_g2l(const void* g, void* l) {
    __builtin_amdgcn_global_load_lds((const __attribute__((address_space(1))) u32*)g,
                                     (__attribute__((address_space(3))) u32*)l, 16, 0, 0);
}

// ---------------- prep: ALL weight conversions ----------------
__global__ void prep_all(const float* __restrict__ W_h2h, const float* __restrict__ W_i2h,
                         const float* __restrict__ W_ih, const float* __restrict__ W_hh,
                         const float* __restrict__ b_ih, const float* __restrict__ b_hh,
                         const float* __restrict__ W_gen,
                         char* __restrict__ Wh2h_q8, u16* __restrict__ Wi2h_bf,
                         u16* __restrict__ Wcat3, float* __restrict__ bsum,
                         u16* __restrict__ WgenP, float* __restrict__ WohT) {
    int idx = blockIdx.x * 256 + threadIdx.x;  // 65536 threads
    if (idx < 65536) {
        Wh2h_q8[idx] = (char)q8i(W_h2h[idx], SW);
        Wi2h_bf[idx] = f2bf(W_i2h[idx]);
    }
    for (int i = idx; i < 16 * 16 * 4 * 64 * 8; i += 65536) {
        int j = i & 7, lane = (i >> 3) & 63, q = (i >> 9) & 3, ks = (i >> 11) & 15, ub = i >> 15;
        int lr = lane & 15, lq = lane >> 4;
        int rg = q * 256 + ub * 16 + lr;
        int k = ks * 32 + lq * 8 + j;
        float v = (k < 256) ? W_ih[(size_t)rg * 356 + k] : W_hh[(size_t)rg * 256 + (k - 256)];
        Wcat3[i] = f2bf(v);
    }
    for (int i = idx; i < 100 * 1024; i += 65536) {
        int t = i >> 10, rg = i & 1023;
        WohT[i] = W_ih[(size_t)rg * 356 + 256 + t];
    }
    if (idx < 1024) bsum[idx] = b_ih[idx] + b_hh[idx];
    if (idx < 32768) {
        int r = idx >> 8, ccol = idx & 255;
        WgenP[idx] = (r < NCLS) ? f2bf(W_gen[r * 256 + ccol]) : (u16)0;
    }
}

// ---------------- proj_H GEMM: 1 batch/block, 128x256, 8 waves 2x4 --------
// Writes projF8 [b][h][t] int8 and bHf8 [b][t][i] int8 (direct, no transpose).
__launch_bounds__(512, 3)
__global__ void gemm_projH5(const float* __restrict__ bH, const u16* __restrict__ Wi2h_bf,
                            char* __restrict__ projF8, char* __restrict__ bHf8) {
    __shared__ char gsm[49152];
    u16* As[2] = {(u16*)gsm, (u16*)(gsm + 8192)};
    u16* Bs[2] = {(u16*)(gsm + 16384), (u16*)(gsm + 32768)};
    char* Tt = gsm;   // epilogue: [256 rows][144 pad] int8 (aliases As after final sync)

    int b = blockIdx.x, tid = threadIdx.x;
    int wave = tid >> 6, lane = tid & 63, lr = lane & 15, lq = lane >> 4;
    int wm = wave >> 2, wn = wave & 3;
    int ar = tid >> 2, part = tid & 3;
    const float* asrc = bH + ((size_t)b * 128 + ar) * 256 + part * 8;
    f32x4 acc[4][4] = {};
    uint2 bh[8];

    auto stageB = [&](int kc, int buf) {
        for (int i = 0; i < 2; i++) {
            int ch = wave * 2 + i;
            int row = ch * 16 + (lane >> 2);
            const u16* g = Wi2h_bf + (size_t)row * 256 + kc * 32 + (lane & 3) * 8;
            async_g2l(g, (char*)Bs[buf] + ch * 1024 + lane * 16);
        }
    };
    auto writeA = [&](int kc, int buf, float4 v0, float4 v1) {
        u16* dst = As[buf] + ar * 32 + part * 8;
        dst[0] = f2bf(v0.x); dst[1] = f2bf(v0.y); dst[2] = f2bf(v0.z); dst[3] = f2bf(v0.w);
        dst[4] = f2bf(v1.x); dst[5] = f2bf(v1.y); dst[6] = f2bf(v1.z); dst[7] = f2bf(v1.w);
        uint p0 = (uint)(u8)q8i(v0.x, SH) | ((uint)(u8)q8i(v0.y, SH) << 8) |
                  ((uint)(u8)q8i(v0.z, SH) << 16) | ((uint)(u8)q8i(v0.w, SH) << 24);
        uint p1 = (uint)(u8)q8i(v1.x, SH) | ((uint)(u8)q8i(v1.y, SH) << 8) |
                  ((uint)(u8)q8i(v1.z, SH) << 16) | ((uint)(u8)q8i(v1.w, SH) << 24);
        bh[kc].x = p0; bh[kc].y = p1;
    };

    float4 a0 = *(const float4*)(asrc);
    float4 a1 = *(const float4*)(asrc + 4);
    stageB(0, 0);
    writeA(0, 0, a0, a1);
    __syncthreads();

    for (int kc = 0; kc < 8; kc++) {
        int cur = kc & 1, nxt = cur ^ 1;
        if (kc < 7) {
            stageB(kc + 1, nxt);
            a0 = *(const float4*)(asrc + (kc + 1) * 32);
            a1 = *(const float4*)(asrc + (kc + 1) * 32 + 4);
        }
        short8 af[4];
        for (int mi = 0; mi < 4; mi++)
            af[mi] = *(const short8*)(As[cur] + (wm * 64 + mi * 16 + lr) * 32 + lq * 8);
        for (int ni = 0; ni < 4; ni++) {
            short8 bf = *(const short8*)(Bs[cur] + (wn * 64 + ni * 16 + lr) * 32 + lq * 8);
            for (int mi = 0; mi < 4; mi++)
                acc[mi][ni] = __builtin_amdgcn_mfma_f32_16x16x32_bf16(af[mi], bf, acc[mi][ni], 0, 0, 0);
        }
        if (kc < 7) writeA(kc + 1, nxt, a0, a1);
        __syncthreads();
    }

    // bHf8 [b][t][i]: straight from the A-quant registers, coalesced uint2 stores.
    for (int kc = 0; kc < 8; kc++)
        *(uint2*)(bHf8 + (size_t)b * 32768 + ar * 256 + kc * 32 + part * 8) = bh[kc];

    // projF8 transpose epilogue (int8 [b][h][t])
    for (int mi = 0; mi < 4; mi++)
        for (int ni = 0; ni < 4; ni++) {
            int h = wn * 64 + ni * 16 + lr;
            int t = wm * 64 + mi * 16 + lq * 4;
            f32x4 v = acc[mi][ni];
            uint pk = (uint)(u8)q8i(v[0], SP) | ((uint)(u8)q8i(v[1], SP) << 8) |
                      ((uint)(u8)q8i(v[2], SP) << 16) | ((uint)(u8)q8i(v[3], SP) << 24);
            *(uint*)(Tt + h * 144 + t) = pk;
        }
    __syncthreads();
    {
        int hrow = tid >> 1, half = tid & 1;
        const char* src = Tt + hrow * 144 + half * 64;
        char* dst = projF8 + (size_t)b * 32768 + hrow * 128 + half * 64;
        uint4 v0 = *(const uint4*)(src);
        uint4 v1 = *(const uint4*)(src + 16);
        uint4 v2 = *(const uint4*)(src + 32);
        uint4 v3 = *(const uint4*)(src + 48);
        *(uint4*)(dst) = v0; *(uint4*)(dst + 16) = v1;
        *(uint4*)(dst + 32) = v2; *(uint4*)(dst + 48) = v3;
    }
}

// ---------------- persistent block-local step loop: 256 blocks x 512 threads ----------
// Each block owns 2 batches end-to-end. All recurrent state is block-local:
// c in registers, h in LDS, projF8/bHf8 pinned in LDS for all 26 steps.
// NO grid syncs, NO device fences -> caches stay warm. Streams Wcat3 (1MB) per step.
#define OFF_PROJ 0          // [2][256][128] int8, t-chunk XOR swizzled
#define OFF_BH   65536      // [2][128][256] int8, t-major (plain)
#define OFF_XT   131072     // u16 [2][512]  X = [ctx;h]
#define OFF_ZB   133120     // 64B zero block (A-frag rows >=2)
#define OFF_PH   133184     // f32 [2][256]
#define OFF_GC   135232     // f32 [2][4][256]  gates | ctx partials (aliased)
#define OFF_EP   143424     // f32 [2][128*4]   e partials
#define OFF_ES   147520     // f32 [2][128]     exp(e-m)
#define OFF_H8   148544     // char [2][256]
#define OFF_WS   149056     // f32 [256] W_score
#define OFF_B2   150080     // f32 [256] b_h2h
#define OFF_TG   151104     // int [2][26]
#define OFF_RI   151360     // f32 [2]
#define LDS_TOT  151424

__launch_bounds__(512, 1)
__global__ void step_loop2(const char* __restrict__ projF8, const char* __restrict__ bHf8,
                           const char* __restrict__ Wh2h_q8, const float* __restrict__ b_h2h,
                           const float* __restrict__ W_score, const u16* __restrict__ Wcat3,
                           const float* __restrict__ bsum, const float* __restrict__ WohT,
                           const int* __restrict__ text, u16* __restrict__ hbf_all) {
    __shared__ __align__(16) char Lm[LDS_TOT];
    u16* Xt = (u16*)(Lm + OFF_XT);
    u16* zb = (u16*)(Lm + OFF_ZB);
    float* phL = (float*)(Lm + OFF_PH);
    float* gcF = (float*)(Lm + OFF_GC);
    float* epL = (float*)(Lm + OFF_EP);
    float* esL = (float*)(Lm + OFF_ES);
    char* h8c = Lm + OFF_H8;
    float* wsL = (float*)(Lm + OFF_WS);
    float* b2L = (float*)(Lm + OFF_B2);
    int* tgL = (int*)(Lm + OFF_TG);
    float* riL = (float*)(Lm + OFF_RI);

    int blk = blockIdx.x, tid = threadIdx.x;
    int lane = tid & 63;
    int b = tid >> 8, htid = tid & 255;      // batch-half decomposition
    int wv4 = (tid >> 6) & 3;                // wave within half
    int tq = htid & 7, hg = htid >> 3;       // e-phase: t-chunk, h-group (hg in [0,32))
    int wv = tid >> 6;                       // wave 0..7 (LSTM: ub pair)
    int lr = lane & 15, lq = lane >> 4;

    // ---- prologue: stage activations into LDS, init state ----
    {
        const uint4* pg = (const uint4*)(projF8 + (size_t)blk * 65536);
        const uint4* bg = (const uint4*)(bHf8 + (size_t)blk * 65536);
#pragma unroll
        for (int q = 0; q < 8; q++) {
            int w = tid + q * 512;           // uint4 index in [0,4096)
            int c = w & 7;                   // t-chunk
            int R = (w >> 3) & 255;          // h row
            int b2 = w >> 11;                // batch 0/1
            uint4 v = pg[w];
            *(uint4*)(Lm + b2 * 32768 + R * 128 + (((c ^ (R >> 3)) & 7) << 4)) = v;
            *(uint4*)(Lm + OFF_BH + w * 16) = bg[w];
        }
        if (tid < 128) *(uint*)(Lm + OFF_XT + 512 + tid * 4) = 0;          // Xt[0] h-half
        else if (tid < 256) *(uint*)(Lm + OFF_XT + 1536 + (tid - 128) * 4) = 0;  // Xt[1] h-half
        if (tid < 16) *(uint*)(Lm + OFF_ZB + tid * 4) = 0;
        if (tid < 256) { wsL[tid] = W_score[tid]; b2L[tid] = b_h2h[tid]; }
        if (tid < 52) {
            int bb = tid >= 26, st = tid - bb * 26;
            tgL[bb * 26 + st] = text[(blk * 2 + bb) * NSTEP + st];
        }
    }
    __syncthreads();

    float creg = 0.f;    // c state for (b = tid>>8, u = tid&255)

    for (int s = 0; s < NSTEP; s++) {
        // ---- phase A: ph[b][u] = b_h2h[u] + (h8 . Wh2h_q8[u]) / (SW*S8) ----
        {
            int u = htid;
            float v;
            if (s == 0) {
                v = b2L[u];
            } else {
                const uint4* wrow = (const uint4*)(Wh2h_q8 + (size_t)u * 256);
                const uint4* hv = (const uint4*)(h8c + b * 256);
                int acc = 0;
#pragma unroll
                for (int k = 0; k < 16; k++) {
                    uint4 w = wrow[k];
                    uint4 hh = hv[k];
#ifdef HAS_SDOT4
                    acc = __builtin_amdgcn_sdot4((int)w.x, (int)hh.x, acc, false);
                    acc = __builtin_amdgcn_sdot4((int)w.y, (int)hh.y, acc, false);
                    acc = __builtin_amdgcn_sdot4((int)w.z, (int)hh.z, acc, false);
                    acc = __builtin_amdgcn_sdot4((int)w.w, (int)hh.w, acc, false);
#else
                    uint wv_[4] = {w.x, w.y, w.z, w.w}, hv_[4] = {hh.x, hh.y, hh.z, hh.w};
                    for (int c = 0; c < 4; c++)
                        for (int by = 0; by < 32; by += 8)
                            acc += (int)(char)(wv_[c] >> by) * (int)(char)(hv_[c] >> by);
#endif
                }
                v = (float)acc * (1.f / (SW * S8)) + b2L[u];
            }
            phL[b * 256 + u] = v;
        }
        __syncthreads();

        // ---- phase B: e[t] = sum_h tanh(proj/SP + ph[h]) * Ws[h]; LDS reads ----
        {
            const __half2 c3 = __float2half2_rn(-0.0016249f), c2 = __float2half2_rn(0.031520f);
            const __half2 c1 = __float2half2_rn(-0.222110f), c0 = __float2half2_rn(0.962117f);
            const float inv = 1.f / SP;
            int t0e = tq * 16;
            int co = ((tq ^ hg) & 7) << 4;   // swizzled chunk offset (R>>3 == hg for all 8 rows)
            __half2 acc2[8];
#pragma unroll
            for (int q = 0; q < 8; q++) acc2[q] = __float2half2_rn(0.f);
            const char* baseL = Lm + b * 32768 + co;
#pragma unroll
            for (int hh = 0; hh < 8; hh++) {
                int R = hg * 8 + hh;
                uint4 uu = *(const uint4*)(baseL + R * 128);
                float phv = phL[b * 256 + R];
                __half2 wv2 = __float2half2_rn(wsL[R]);
                uint wq[4] = {uu.x, uu.y, uu.z, uu.w};
#pragma unroll
                for (int wi = 0; wi < 4; wi++) {
                    uint w = wq[wi];
#pragma unroll
                    for (int pp = 0; pp < 2; pp++) {
                        float xa = fmaf((float)(char)(w >> (pp * 16)), inv, phv);
                        float xb = fmaf((float)(char)(w >> (pp * 16 + 8)), inv, phv);
                        xa = fminf(fmaxf(xa, -3.0f), 3.0f);
                        xb = fminf(fmaxf(xb, -3.0f), 3.0f);
                        __half2 x = __floats2half2_rn(xa, xb);
                        __half2 u2 = __hmul2(x, x);
                        __half2 p = __hfma2(__hfma2(__hfma2(c3, u2, c2), u2, c1), u2, c0);
                        acc2[wi * 2 + pp] = __hfma2(__hmul2(x, p), wv2, acc2[wi * 2 + pp]);
                    }
                }
            }
            float a16[16];
#pragma unroll
            for (int q = 0; q < 8; q++) {
                a16[q * 2] = __low2float(acc2[q]);
                a16[q * 2 + 1] = __high2float(acc2[q]);
            }
#pragma unroll
            for (int j = 0; j < 16; j++) {
                float v = a16[j];
                v += __shfl_xor(v, 8);
                v += __shfl_xor(v, 16);
                v += __shfl_xor(v, 32);
                a16[j] = v;
            }
            if (lane < 8) {
                int t0w = lane * 16;
#pragma unroll
                for (int j = 0; j < 16; j++) epL[b * 512 + (t0w + j) * 4 + wv4] = a16[j];
            }
        }
        __syncthreads();

        // ---- phase C: softmax (wave 0 of each half) ----
        if (wv4 == 0) {
            int t0 = lane * 2;
            float e0 = 0.f, e1 = 0.f;
#pragma unroll
            for (int w = 0; w < 4; w++) {
                e0 += epL[b * 512 + t0 * 4 + w];
                e1 += epL[b * 512 + (t0 + 1) * 4 + w];
            }
            float m = fmaxf(e0, e1);
            for (int o = 32; o >= 1; o >>= 1) m = fmaxf(m, __shfl_xor(m, o));
            float x0 = __expf(e0 - m), x1 = __expf(e1 - m);
            float ss = x0 + x1;
            for (int o = 32; o >= 1; o >>= 1) ss += __shfl_xor(ss, o);
            esL[b * 128 + t0] = x0; esL[b * 128 + t0 + 1] = x1;
            if (lane == 0) riL[b] = 1.f / ss;
        }
        __syncthreads();

        // ---- phase D: context partials; t-major LDS, conflict-free ----
        {
            int slice = htid >> 6, ig = htid & 63;   // t in [slice*32, +32), i = ig*4..+3
            const char* bsrc = Lm + OFF_BH + b * 32768 + slice * 32 * 256 + ig * 4;
            const float* es = esL + b * 128 + slice * 32;
            float a0 = 0.f, a1 = 0.f, a2 = 0.f, a3 = 0.f;
#pragma unroll
            for (int t = 0; t < 32; t++) {
                float al = es[t];
                uint v = *(const uint*)(bsrc + t * 256);
                a0 += al * (float)(char)(v);
                a1 += al * (float)(char)(v >> 8);
                a2 += al * (float)(char)(v >> 16);
                a3 += al * (float)(char)(v >> 24);
            }
            float* cp = gcF + (b * 4 + slice) * 256 + ig * 4;
            cp[0] = a0; cp[1] = a1; cp[2] = a2; cp[3] = a3;
        }
        __syncthreads();

        // ---- phase E: reduce partials -> Xtile ctx half (bf16) ----
        {
            int i = htid;
            float sm = gcF[(b * 4 + 0) * 256 + i] + gcF[(b * 4 + 1) * 256 + i] +
                       gcF[(b * 4 + 2) * 256 + i] + gcF[(b * 4 + 3) * 256 + i];
            Xt[b * 512 + i] = f2bf(sm * riL[b] * (1.f / SH));
        }
        __syncthreads();

        // ---- phase F: LSTM GEMM, wave wv handles ub = 2wv, 2wv+1; streams Wcat3 ----
        {
            const u16* xsrc = (lr < 2) ? (Xt + lr * 512) : zb;
            int xstep = (lr < 2) ? 1 : 0;    // advance only for valid rows
            f32x4 ac[2][4] = {};
#pragma unroll 4
            for (int ks = 0; ks < 16; ks++) {
                short8 af = *(const short8*)(xsrc + (ks * 32 + lq * 8) * xstep);
#pragma unroll
                for (int uu = 0; uu < 2; uu++) {
                    int ub = wv * 2 + uu;
                    const u16* wb = Wcat3 + ((size_t)((ub * 16 + ks) * 4)) * 512 + lane * 8;
#pragma unroll
                    for (int g = 0; g < 4; g++)
                        ac[uu][g] = __builtin_amdgcn_mfma_f32_16x16x32_bf16(
                            af, *(const short8*)(wb + g * 512), ac[uu][g], 0, 0, 0);
                }
            }
            if (lq == 0) {
#pragma unroll
                for (int uu = 0; uu < 2; uu++) {
                    int ub = wv * 2 + uu;
#pragma unroll
                    for (int g = 0; g < 4; g++) {
                        gcF[(0 * 4 + g) * 256 + ub * 16 + lr] = ac[uu][g][0];
                        gcF[(1 * 4 + g) * 256 + ub * 16 + lr] = ac[uu][g][1];
                    }
                }
            }
        }
        __syncthreads();

        // ---- phase G: pointwise LSTM; c in register, h -> LDS + hbf_all ----
        {
            int u = htid;
            int tgt = tgL[b * 26 + s];
            const float* wt = WohT + (size_t)tgt * 1024;
            float gi = gcF[(b * 4 + 0) * 256 + u] + bsum[u] + wt[u];
            float gf = gcF[(b * 4 + 1) * 256 + u] + bsum[256 + u] + wt[256 + u];
            float gg = gcF[(b * 4 + 2) * 256 + u] + bsum[512 + u] + wt[512 + u];
            float go = gcF[(b * 4 + 3) * 256 + u] + bsum[768 + u] + wt[768 + u];
            float cn = fast_sig(gf) * creg + fast_sig(gi) * fast_tanh(gg);
            float hn = fast_sig(go) * fast_tanh(cn);
            creg = cn;
            hbf_all[(size_t)s * NB * NH + (size_t)(blk * 2 + b) * 256 + u] = f2bf(hn);
            h8c[b * 256 + u] = (char)q8i(hn, S8);
            Xt[b * 512 + 256 + u] = f2bf(hn);
        }
        __syncthreads();
    }
}

// ---------------- final logits ----------------
__launch_bounds__(256)
__global__ void gen_logits(const u16* __restrict__ hbf_all, const u16* __restrict__ WgenP,
                           const float* __restrict__ b_gen, float* __restrict__ out) {
    __shared__ u16 As[32 * 32];
    __shared__ u16 Bs[128 * 32];
    int mb = blockIdx.x;
    int tid = threadIdx.x;
    int wave = tid >> 6, lane = tid & 63, lr = lane & 15, lq = lane >> 4;
    int wm = wave >> 1, wn = wave & 1;
    f32x4 acc[4] = {};
    for (int kc = 0; kc < 256; kc += 32) {
        __syncthreads();
        {
            int r = tid >> 3, c4 = (tid & 7) * 4;
            *(ushort4*)(As + r * 32 + c4) =
                *(const ushort4*)(hbf_all + (size_t)(mb * 32 + r) * 256 + kc + c4);
        }
        {
            int r = tid >> 1, h16 = (tid & 1) * 16;
            const u16* src = WgenP + (size_t)r * 256 + kc + h16;
            u16* d = Bs + r * 32 + h16;
            *(ushort4*)(d) = *(const ushort4*)(src);
            *(ushort4*)(d + 4) = *(const ushort4*)(src + 4);
            *(ushort4*)(d + 8) = *(const ushort4*)(src + 8);
            *(ushort4*)(d + 12) = *(const ushort4*)(src + 12);
        }
        __syncthreads();
        short8 a = *reinterpret_cast<const short8*>(As + (wm * 16 + lr) * 32 + lq * 8);
        for (int ni = 0; ni < 4; ni++) {
            short8 bb = *reinterpret_cast<const short8*>(Bs + (wn * 64 + ni * 16 + lr) * 32 + lq * 8);
            acc[ni] = __builtin_amdgcn_mfma_f32_16x16x32_bf16(a, bb, acc[ni], 0, 0, 0);
        }
    }
    for (int ni = 0; ni < 4; ni++) {
        int cidx = wn * 64 + ni * 16 + lr;
        if (cidx >= NCLS) continue;
        float bg = b_gen[cidx];
        int mbase = mb * 32 + wm * 16 + lq * 4;
        for (int r = 0; r < 4; r++) {
            int mm = mbase + r;
            int s = mm >> 9;
            int bb_ = mm & 511;
            float v = (cidx == 3) ? -10000.f : (acc[ni][r] + bg);
            out[(size_t)bb_ * (NSTEP * NCLS) + s * NCLS + cidx] = v;
        }
    }
}

extern "C" void kernel_launch(void* const* d_in, const int* in_sizes, int n_in,
                              void* d_out, int out_size, void* d_ws, size_t ws_size,
                              hipStream_t stream) {
    const float* batch_H = (const float*)d_in[0];
    const int* text = (const int*)d_in[1];
    const float* W_i2h = (const float*)d_in[3];
    const float* W_h2h = (const float*)d_in[4];
    const float* b_h2h = (const float*)d_in[5];
    const float* W_score = (const float*)d_in[6];
    const float* W_ih = (const float*)d_in[7];
    const float* W_hh = (const float*)d_in[8];
    const float* b_ih = (const float*)d_in[9];
    const float* b_hh = (const float*)d_in[10];
    const float* W_gen = (const float*)d_in[11];
    const float* b_gen = (const float*)d_in[12];
    float* out = (float*)d_out;

    char* ws = (char*)d_ws;
    size_t off = 0;
    auto alloc = [&](size_t bytes) {
        void* p = ws + off;
        off += (bytes + 255) & ~(size_t)255;
        return p;
    };
    char* projF8 = (char*)alloc((size_t)16777216);    // [b][h][t] int8
    char* bHf8 = (char*)alloc((size_t)16777216);      // [b][t][i] int8
    char* Wh2h_q8 = (char*)alloc(65536);
    u16* Wi2h_bf = (u16*)alloc(65536 * 2);
    u16* Wcat3 = (u16*)alloc((size_t)524288 * 2);     // frag-swizzled LSTM weights
    float* bsum = (float*)alloc(1024 * 4);
    u16* WgenP = (u16*)alloc(32768 * 2);
    float* WohT = (float*)alloc((size_t)102400 * 4);  // [100][1024]
    u16* hbf_all = (u16*)alloc((size_t)NSTEP * NB * NH * 2);

    prep_all<<<256, 256, 0, stream>>>(W_h2h, W_i2h, W_ih, W_hh, b_ih, b_hh, W_gen,
                                      Wh2h_q8, Wi2h_bf, Wcat3, bsum, WgenP, WohT);
    gemm_projH5<<<512, 512, 0, stream>>>(batch_H, Wi2h_bf, projF8, bHf8);
    step_loop2<<<256, 512, 0, stream>>>(projF8, bHf8, Wh2h_q8, b_h2h, W_score,
                                        Wcat3, bsum, WohT, text, hbf_all);
    gen_logits<<<416, 256, 0, stream>>>(hbf_all, WgenP, b_gen, out);
}